// Round 4
// baseline (709.709 us; speedup 1.0000x reference)
//
#include <hip/hip_runtime.h>

#define B_    16
#define T_    8192
#define D_    512
#define K_    8192
#define S_    1024
#define N_    16384      // B_*S_
#define NBT   131072     // B_*T_

// d_out float offsets
#define LOSS_OFF 67108864
#define IDX_OFF  67108865
#define BND_OFF  67239937

typedef __bf16 bf16x8 __attribute__((ext_vector_type(8)));
typedef float  f32x4  __attribute__((ext_vector_type(4)));

__device__ __forceinline__ unsigned int fsort(float f){
  unsigned int u = __float_as_uint(f);
  return (u & 0x80000000u) ? ~u : (u | 0x80000000u);
}
__device__ __forceinline__ float funsort(unsigned int su){
  unsigned int u = (su & 0x80000000u) ? (su ^ 0x80000000u) : ~su;
  return __uint_as_float(u);
}
__device__ __forceinline__ unsigned short f2bf(float f){
  unsigned int u = __float_as_uint(f);
  return (unsigned short)((u + 0x7fffu + ((u >> 16) & 1u)) >> 16);
}
__device__ __forceinline__ void gload16(const void* g, void* l){
  __builtin_amdgcn_global_load_lds((const __attribute__((address_space(1))) void*)g,
                                   (__attribute__((address_space(3))) void*)l, 16, 0, 0);
}

// no "memory" clobber: keep the compiler's waitcnt inserter from draining the
// ring (global_load_lds completion is tracked in vmcnt; a clobbered asm would
// force s_waitcnt vmcnt(0) before it). Ordering of side-effecting ops across
// volatile asm is preserved by the machine scheduler.
#define VMW8()  asm volatile("s_waitcnt vmcnt(8)")
#define VMW4()  asm volatile("s_waitcnt vmcnt(4)")
#define VMW0()  asm volatile("s_waitcnt vmcnt(0)")
#define LGKW()  asm volatile("s_waitcnt lgkmcnt(0)")
// inline-asm ds_read_b128: invisible to compiler alias/waitcnt analysis;
// ordering is manual (LGKW + sched_barrier(0) before MFMA consumes results).
// "=&v": early-clobber so dst tuple never overlaps the address register.
#define DSR(dst, addr, OFF) \
  asm volatile("ds_read_b128 %0, %1 offset:" OFF : "=&v"(dst) : "v"(addr))

// |emb_k|^2 (one wave per codebook row) + bf16 copy of emb; block 0 inits cnt
__global__ void k_embnorm(const float4* __restrict__ emb4, float* __restrict__ enorm,
                          unsigned short* __restrict__ embh, int* __restrict__ cnt){
  if(blockIdx.x == 0 && threadIdx.x == 0) *cnt = 0;
  const int wid  = (blockIdx.x * blockDim.x + threadIdx.x) >> 6;   // 0..8191
  const int lane = threadIdx.x & 63;
  float4 a = emb4[wid * 128 + (lane << 1)];
  float4 b = emb4[wid * 128 + (lane << 1) + 1];
  float s = a.x*a.x + a.y*a.y + a.z*a.z + a.w*a.w
          + b.x*b.x + b.y*b.y + b.z*b.z + b.w*b.w;
  #pragma unroll
  for(int off = 32; off; off >>= 1) s += __shfl_xor(s, off);
  if(lane == 0) enorm[wid] = s;
  unsigned short* dst = embh + ((size_t)wid << 9) + (lane << 3);
  *(ushort4*)(dst)     = make_ushort4(f2bf(a.x), f2bf(a.y), f2bf(a.z), f2bf(a.w));
  *(ushort4*)(dst + 4) = make_ushort4(f2bf(b.x), f2bf(b.y), f2bf(b.z), f2bf(b.w));
}

// Fused: boundary (fp64 dot, parallel over 128 lanes) + mean-pool + bf16 convert.
// One block = 32 t-rows = 4 segments; reads x exactly once.
__launch_bounds__(256)
__global__ void k_prep(const float4* __restrict__ x4, const float4* __restrict__ wb4,
                       const float* __restrict__ bb, float4* __restrict__ pooled4,
                       unsigned short* __restrict__ pooledh, float* __restrict__ bnd,
                       int* __restrict__ cnt){
  __shared__ double ld[4][8][8];          // [seg_l][row_l][16-lane group]
  const int tid  = threadIdx.x;
  const int row0 = blockIdx.x << 5;       // first global t-row of this block
  const double bbv = (double)bb[0];
  #pragma unroll
  for(int it = 0; it < 2; it++){
    const int slot  = (it << 8) + tid;    // 0..511 = (seg_l:4) x (c4:128)
    const int seg_l = slot >> 7;
    const int c4    = slot & 127;
    const float4 w  = wb4[c4];
    const float4* src = x4 + ((size_t)(row0 + (seg_l << 3)) * 128 + c4);
    float4 acc = src[0];
    double p[8];
    p[0] = (double)acc.x*w.x + (double)acc.y*w.y + (double)acc.z*w.z + (double)acc.w*w.w;
    #pragma unroll
    for(int t = 1; t < 8; t++){
      const float4 v = src[(size_t)t * 128];
      acc.x += v.x; acc.y += v.y; acc.z += v.z; acc.w += v.w;
      p[t] = (double)v.x*w.x + (double)v.y*w.y + (double)v.z*w.z + (double)v.w*w.w;
    }
    acc.x *= 0.125f; acc.y *= 0.125f; acc.z *= 0.125f; acc.w *= 0.125f;
    const int u = ((blockIdx.x << 2) + seg_l) * 128 + c4;
    pooled4[u] = acc;
    *(ushort4*)(pooledh + ((size_t)u << 2)) =
        make_ushort4(f2bf(acc.x), f2bf(acc.y), f2bf(acc.z), f2bf(acc.w));
    #pragma unroll
    for(int t = 0; t < 8; t++){
      #pragma unroll
      for(int off = 1; off < 16; off <<= 1) p[t] += __shfl_xor(p[t], off);
    }
    if((c4 & 15) == 0){
      #pragma unroll
      for(int t = 0; t < 8; t++) ld[seg_l][t][c4 >> 4] = p[t];
    }
  }
  __syncthreads();
  if(tid < 32){
    const double* q = ld[tid >> 3][tid & 7];
    double s = bbv;
    #pragma unroll
    for(int h = 0; h < 8; h++) s += q[h];
    const bool f = s > 0.0;
    bnd[row0 + tid] = f ? 1.0f : 0.0f;
    const unsigned long long m = __ballot(f);
    if(tid == 0) atomicAdd(cnt, (int)__popcll(m));
  }
}

// bf16 MFMA distance GEMM, 256x256 tile, 8 waves, BK=32, 4-deep LDS ring.
// Two fine phases per K-step: {asm ds_read frags || 2 gload_lds -> s_barrier ->
// lgkmcnt(0)+sched_barrier(0) -> setprio(1) 16 MFMA setprio(0) -> s_barrier};
// vmcnt(8) counted once per step (2 steps of staging in flight, never drained).
// launch_bounds(512,2): 2 waves/EU budget (~256 VGPR) keeps acc[8][4] in arch
// VGPRs (no per-MFMA accvgpr shuttling). XOR-swizzled LDS (linear gload dest +
// pre-swizzled source + swizzled read addr). XCD slab swizzle for L2 locality.
__launch_bounds__(512, 2)
__global__ void k_distx(const unsigned short* __restrict__ Ah,
                        const unsigned short* __restrict__ Bh,
                        const float* __restrict__ enorm,
                        unsigned long long* __restrict__ cand64){
  // 4 ring buffers, each: A 256x32 bf16 (16KB) + B 256x32 (16KB) = 32KB
  __shared__ __align__(16) unsigned short smem[65536];   // 128 KB

  const int tid  = threadIdx.x;
  const int w    = tid >> 6, lane = tid & 63;
  const int wm   = w >> 2,  wn   = w & 3;        // 2x4 wave grid; wave = 128x64 out
  const int c    = lane & 15, q  = lane >> 4;

  const int bid   = blockIdx.x;
  const int xcd   = bid & 7;
  const int local = bid >> 3;                    // 0..255 within XCD
  const int row_t = (xcd << 3) + (local & 7);    // 0..63  (8-row-tile slab per XCD)
  const int col_t = local >> 3;                  // 0..31  (col-major sweep)
  const int rowbase = row_t << 8;
  const int colbase = col_t << 8;

  f32x4 acc[8][4];
  #pragma unroll
  for(int i = 0; i < 8; i++)
    #pragma unroll
    for(int j = 0; j < 4; j++) acc[i][j] = (f32x4){0.f, 0.f, 0.f, 0.f};

  // ---- staging geometry: LDS row = tid>>2 (+128), LDS chunk = tid&3 (16B units).
  // LDS(row, chunk) holds global(row, chunk ^ ((row>>1)&3)) -> pre-swizzle source.
  const int sr  = tid >> 2;                      // 0..127
  const int cg  = (((tid & 3) ^ ((tid >> 3) & 3)) << 3);   // swizzled k-chunk (elements)
  const int wbase = w << 9;                      // wave-uniform LDS base (ushorts)

  const unsigned short* As0 = Ah + (size_t)(rowbase + sr)       * 512 + cg;
  const unsigned short* As1 = Ah + (size_t)(rowbase + 128 + sr) * 512 + cg;
  const unsigned short* Bs0 = Bh + (size_t)(colbase + sr)       * 512 + cg;
  const unsigned short* Bs1 = Bh + (size_t)(colbase + 128 + sr) * 512 + cg;

  // read-side swizzle (byte addrs): chunk_l = q ^ ((row>>1)&3); row&15 == c
  const int chb = ((q ^ ((c >> 1) & 3)) << 4);             // byte offset within row
  const int abA = (wm*128 + c)*64 + chb;                   // A frag byte base
  const int abB = 16384 + (wn*64 + c)*64 + chb;            // B frag byte base

  bf16x8 af[4], bg[4];

  #define SA(tt) do{ const int sb_ = ((tt) & 3) << 14; const size_t ko_ = (size_t)(tt) << 5; \
    gload16(As0 + ko_, &smem[sb_ + wbase]);                                                  \
    gload16(As1 + ko_, &smem[sb_ + 4096  + wbase]); }while(0)
  #define SB(tt) do{ const int sb_ = ((tt) & 3) << 14; const size_t ko_ = (size_t)(tt) << 5; \
    gload16(Bs0 + ko_, &smem[sb_ + 8192  + wbase]);                                          \
    gload16(Bs1 + ko_, &smem[sb_ + 12288 + wbase]); }while(0)

  // Phase A: asm-read bg[0..3]+af[0..3] || stage A(t+3); bar; lgkm+sched0; 16 MFMA; bar
  #define PHASE_A(tt, DOST) do{                                             \
    const int la_ = ((tt) & 3) << 15;                                       \
    const int vA_ = abA + la_;                                              \
    const int vB_ = abB + la_;                                              \
    DSR(bg[0], vB_, "0");    DSR(bg[1], vB_, "1024");                       \
    DSR(bg[2], vB_, "2048"); DSR(bg[3], vB_, "3072");                       \
    DSR(af[0], vA_, "0");    DSR(af[1], vA_, "1024");                       \
    DSR(af[2], vA_, "2048"); DSR(af[3], vA_, "3072");                       \
    if(DOST) SA((tt) + 3);                                                  \
    __builtin_amdgcn_s_barrier();                                           \
    LGKW();                                                                 \
    __builtin_amdgcn_sched_barrier(0);                                      \
    __builtin_amdgcn_s_setprio(1);                                          \
    _Pragma("unroll")                                                       \
    for(int i = 0; i < 4; i++)                                              \
      _Pragma("unroll")                                                     \
      for(int j = 0; j < 4; j++)                                            \
        acc[i][j] = __builtin_amdgcn_mfma_f32_16x16x32_bf16(af[i], bg[j], acc[i][j], 0, 0, 0); \
    __builtin_amdgcn_s_setprio(0);                                          \
    __builtin_amdgcn_s_barrier();                                           \
  }while(0)

  // Phase B: asm-read af[4..7] || stage B(t+3); bar; lgkm+sched0; 16 MFMA (caller closes)
  #define PHASE_B(tt, DOST) do{                                             \
    const int la_ = ((tt) & 3) << 15;                                       \
    const int vA_ = abA + la_;                                              \
    DSR(af[0], vA_, "4096"); DSR(af[1], vA_, "5120");                       \
    DSR(af[2], vA_, "6144"); DSR(af[3], vA_, "7168");                       \
    if(DOST) SB((tt) + 3);                                                  \
    __builtin_amdgcn_s_barrier();                                           \
    LGKW();                                                                 \
    __builtin_amdgcn_sched_barrier(0);                                      \
    __builtin_amdgcn_s_setprio(1);                                          \
    _Pragma("unroll")                                                       \
    for(int i = 0; i < 4; i++)                                              \
      _Pragma("unroll")                                                     \
      for(int j = 0; j < 4; j++)                                            \
        acc[i+4][j] = __builtin_amdgcn_mfma_f32_16x16x32_bf16(af[i], bg[j], acc[i+4][j], 0, 0, 0); \
    __builtin_amdgcn_s_setprio(0);                                          \
  }while(0)

  // prologue: stage steps 0,1,2 (12 loads); wait oldest 4 (step 0) landed
  SA(0); SB(0); SA(1); SB(1); SA(2); SB(2);
  VMW8();
  __builtin_amdgcn_s_barrier();

  // main loop: steps 0..12 stage step t+3; vmcnt(8) keeps steps t+2,t+3 in flight
  #pragma unroll 1
  for(int t = 0; t < 13; ++t){
    PHASE_A(t, 1);
    PHASE_B(t, 1);
    VMW8();
    __builtin_amdgcn_s_barrier();
  }
  // tail: no staging; drain progressively
  PHASE_A(13, 0); PHASE_B(13, 0); VMW4(); __builtin_amdgcn_s_barrier();
  PHASE_A(14, 0); PHASE_B(14, 0); VMW0(); __builtin_amdgcn_s_barrier();
  PHASE_A(15, 0); PHASE_B(15, 0);

  #undef SA
  #undef SB
  #undef PHASE_A
  #undef PHASE_B

  // epilogue: dist = enorm - 2*dot; in-thread top-2 over 4 j-cols, 4-step
  // butterfly over 16 c-lanes -> top-2 per 64-col group; lane c==0 stores u64.
  float en[4];
  #pragma unroll
  for(int j = 0; j < 4; j++) en[j] = enorm[colbase + wn*64 + j*16 + c];

  #pragma unroll
  for(int i = 0; i < 8; i++){
    #pragma unroll
    for(int r = 0; r < 4; r++){
      unsigned int k1 = 0xffffffffu, k2 = 0xffffffffu;
      #pragma unroll
      for(int j = 0; j < 4; j++){
        const float d = fmaf(-2.0f, acc[i][j][r], en[j]);
        const unsigned int col = (unsigned int)(colbase + wn*64 + j*16 + c);
        const unsigned int key = (fsort(d) & 0xffffe000u) | col;
        if(key < k1){ k2 = k1; k1 = key; } else if(key < k2){ k2 = key; }
      }
      #pragma unroll
      for(int off = 1; off < 16; off <<= 1){
        const unsigned int o1 = __shfl_xor(k1, off);
        const unsigned int o2 = __shfl_xor(k2, off);
        if(o1 < k1){ k2 = min(k1, o2); k1 = o1; }
        else       { k2 = min(k2, o1); }
      }
      if(c == 0){
        const int row = rowbase + wm*128 + i*16 + (q << 2) + r;
        cand64[((size_t)row << 7) + (col_t << 2) + wn] =
            ((unsigned long long)k2 << 32) | k1;
      }
    }
  }
}

// fp64 rescore of candidates within margin of min -> exact argmin + per-row loss term
__launch_bounds__(256)
__global__ void k_fixup(const float* __restrict__ pooled, const float* __restrict__ emb,
                        const unsigned long long* __restrict__ cand64,
                        int* __restrict__ idxf, double* __restrict__ part){
  const int lane = threadIdx.x & 63, wv = threadIdx.x >> 6;
  const int row = (blockIdx.x << 2) + wv;
  const ulonglong2* cr = (const ulonglong2*)(cand64 + ((size_t)row << 7));
  const ulonglong2 v = cr[lane];
  unsigned int ks[4];
  ks[0] = (unsigned int)v.x; ks[1] = (unsigned int)(v.x >> 32);
  ks[2] = (unsigned int)v.y; ks[3] = (unsigned int)(v.y >> 32);
  unsigned int mn = min(min(ks[0], ks[1]), min(ks[2], ks[3]));
  #pragma unroll
  for(int off = 32; off; off >>= 1) mn = min(mn, (unsigned int)__shfl_xor(mn, off));
  const float thr = funsort(mn & 0xffffe000u) + 0.01f;   // covers bf16 + key-trunc error

  double bestd = 1e300; int besti = 0x7fffffff;
  const float4* p4 = (const float4*)(pooled + ((size_t)row << 9));
  const float4 pa = p4[lane << 1], pb = p4[(lane << 1) + 1];
  #pragma unroll
  for(int g = 0; g < 4; g++){
    const bool flag = funsort(ks[g] & 0xffffe000u) <= thr;
    unsigned long long mask = __ballot(flag);
    while(mask){
      const int l = __ffsll(mask) - 1;
      mask &= mask - 1;
      const int code = (int)(__shfl(ks[g], l) & 0x1fffu);
      const float4* e4 = (const float4*)(emb + ((size_t)code << 9));
      const float4 ea = e4[lane << 1], eb = e4[(lane << 1) + 1];
      double s = 0.0, d;
      d = (double)pa.x - ea.x; s += d * d;  d = (double)pa.y - ea.y; s += d * d;
      d = (double)pa.z - ea.z; s += d * d;  d = (double)pa.w - ea.w; s += d * d;
      d = (double)pb.x - eb.x; s += d * d;  d = (double)pb.y - eb.y; s += d * d;
      d = (double)pb.z - eb.z; s += d * d;  d = (double)pb.w - eb.w; s += d * d;
      #pragma unroll
      for(int off = 32; off; off >>= 1) s += __shfl_xor(s, off);
      if(s < bestd || (s == bestd && code < besti)){ bestd = s; besti = code; }
    }
  }
  __shared__ double se[4];
  if(lane == 0){ idxf[row] = besti; se[wv] = bestd; }
  __syncthreads();
  if(threadIdx.x == 0) part[blockIdx.x] = se[0] + se[1] + se[2] + se[3];
}

__global__ void k_loss(const double* __restrict__ part, const int* __restrict__ cnt,
                       float* __restrict__ out_loss){
  const int tid = threadIdx.x;
  double s = 0.0;
  for(int i = tid; i < 4096; i += 256) s += part[i];
  #pragma unroll
  for(int off = 32; off; off >>= 1) s += __shfl_xor(s, off);
  __shared__ double sb[4];
  if((tid & 63) == 0) sb[tid >> 6] = s;
  __syncthreads();
  if(tid == 0){
    const double e  = sb[0] + sb[1] + sb[2] + sb[3];
    const double el = e / (double)((size_t)N_ * 512);
    const double bm = (double)(*cnt) / 131072.0 - 0.125;
    const double loss = 0.25 * el + 0.01 * bm * bm;
    *out_loss = (float)loss;
  }
}

// expand codes over SPAN: one wave per segment, 16 coalesced 1KB stores
__launch_bounds__(256)
__global__ void k_expand(const float4* __restrict__ emb4, const int* __restrict__ idxf,
                         float4* __restrict__ q4, float* __restrict__ idxo){
  const int lane = threadIdx.x & 63, wv = threadIdx.x >> 6;
  const int seg = (blockIdx.x << 2) + wv;      // 0..16383
  const int idx = idxf[seg];
  const float4 a = emb4[idx * 128 + (lane << 1)];
  const float4 b = emb4[idx * 128 + (lane << 1) + 1];
  float4* dst = q4 + ((size_t)seg << 10);
  #pragma unroll
  for(int t = 0; t < 8; t++){
    dst[t * 128 + (lane << 1)]     = a;
    dst[t * 128 + (lane << 1) + 1] = b;
  }
  if(lane < 8) idxo[(seg << 3) + lane] = (float)idx;
}

extern "C" void kernel_launch(void* const* d_in, const int* in_sizes, int n_in,
                              void* d_out, int out_size, void* d_ws, size_t ws_size,
                              hipStream_t stream){
  const float* x   = (const float*)d_in[0];
  const float* emb = (const float*)d_in[1];
  const float* wb  = (const float*)d_in[2];
  const float* bb  = (const float*)d_in[3];
  float* out = (float*)d_out;

  // small workspace fields
  char* ws = (char*)d_ws;
  int*    cnt   = (int*)(ws + 0);
  double* part  = (double*)(ws + 64);       // 4096 doubles
  float*  enorm = (float*)(ws + 32832);     // 8192 floats
  int*    idxf  = (int*)(ws + 65600);       // 16384 ints

  // big scratch inside the quantized_out region (overwritten last by k_expand)
  float*              pooled  = (float*)d_out;                                        // 32 MB @ 0
  unsigned long long* cand64  = (unsigned long long*)((char*)d_out + (48ull  << 20)); // 16 MB @ 48M
  unsigned short*     pooledh = (unsigned short*)((char*)d_out + (80ull  << 20));     // 16 MB @ 80M
  unsigned short*     embh    = (unsigned short*)((char*)d_out + (100ull << 20));     //  8 MB @ 100M

  float* bnd   = out + BND_OFF;
  float* idxo  = out + IDX_OFF;
  float* lossp = out + LOSS_OFF;

  hipLaunchKernelGGL(k_embnorm, dim3(2048),  dim3(256), 0, stream, (const float4*)emb, enorm, embh, cnt);
  hipLaunchKernelGGL(k_prep,    dim3(4096),  dim3(256), 0, stream, (const float4*)x, (const float4*)wb,
                     bb, (float4*)pooled, pooledh, bnd, cnt);
  hipLaunchKernelGGL(k_distx,   dim3(2048),  dim3(512), 0, stream, pooledh, embh, enorm, cand64);
  hipLaunchKernelGGL(k_fixup,   dim3(4096),  dim3(256), 0, stream, pooled, emb, cand64, idxf, part);
  hipLaunchKernelGGL(k_loss,    dim3(1),     dim3(256), 0, stream, part, cnt, lossp);
  hipLaunchKernelGGL(k_expand,  dim3(4096),  dim3(256), 0, stream, (const float4*)emb, idxf, (float4*)d_out, idxo);
}

// Round 5
// 701.269 us; speedup vs baseline: 1.0120x; 1.0120x over previous
//
#include <hip/hip_runtime.h>

#define B_    16
#define T_    8192
#define D_    512
#define K_    8192
#define S_    1024
#define N_    16384      // B_*S_
#define NBT   131072     // B_*T_

// d_out float offsets
#define LOSS_OFF 67108864
#define IDX_OFF  67108865
#define BND_OFF  67239937

typedef __bf16 bf16x8 __attribute__((ext_vector_type(8)));
typedef float  f32x4  __attribute__((ext_vector_type(4)));

__device__ __forceinline__ unsigned int fsort(float f){
  unsigned int u = __float_as_uint(f);
  return (u & 0x80000000u) ? ~u : (u | 0x80000000u);
}
__device__ __forceinline__ float funsort(unsigned int su){
  unsigned int u = (su & 0x80000000u) ? (su ^ 0x80000000u) : ~su;
  return __uint_as_float(u);
}
__device__ __forceinline__ unsigned short f2bf(float f){
  unsigned int u = __float_as_uint(f);
  return (unsigned short)((u + 0x7fffu + ((u >> 16) & 1u)) >> 16);
}
__device__ __forceinline__ void gload16(const void* g, void* l){
  __builtin_amdgcn_global_load_lds((const __attribute__((address_space(1))) void*)g,
                                   (__attribute__((address_space(3))) void*)l, 16, 0, 0);
}

#define WAITLGK(n) asm volatile("s_waitcnt lgkmcnt(" #n ")")
#define WAITVM(n)  asm volatile("s_waitcnt vmcnt(" #n ")")
#define SBAR()     __builtin_amdgcn_s_barrier()
#define SCHED0()   __builtin_amdgcn_sched_barrier(0)
#define SETP1()    __builtin_amdgcn_s_setprio(1)
#define SETP0()    __builtin_amdgcn_s_setprio(0)
// inline-asm ds_read_b128: counted-lgkm pipelining is manual; "=&v" early-clobber
#define DSR(dst, addr, OFF) \
  asm volatile("ds_read_b128 %0, %1 offset:" OFF : "=&v"(dst) : "v"(addr))

// |emb_k|^2 (one wave per codebook row) + bf16 copy of emb; block 0 inits cnt
__global__ void k_embnorm(const float4* __restrict__ emb4, float* __restrict__ enorm,
                          unsigned short* __restrict__ embh, int* __restrict__ cnt){
  if(blockIdx.x == 0 && threadIdx.x == 0) *cnt = 0;
  const int wid  = (blockIdx.x * blockDim.x + threadIdx.x) >> 6;   // 0..8191
  const int lane = threadIdx.x & 63;
  float4 a = emb4[wid * 128 + (lane << 1)];
  float4 b = emb4[wid * 128 + (lane << 1) + 1];
  float s = a.x*a.x + a.y*a.y + a.z*a.z + a.w*a.w
          + b.x*b.x + b.y*b.y + b.z*b.z + b.w*b.w;
  #pragma unroll
  for(int off = 32; off; off >>= 1) s += __shfl_xor(s, off);
  if(lane == 0) enorm[wid] = s;
  unsigned short* dst = embh + ((size_t)wid << 9) + (lane << 3);
  *(ushort4*)(dst)     = make_ushort4(f2bf(a.x), f2bf(a.y), f2bf(a.z), f2bf(a.w));
  *(ushort4*)(dst + 4) = make_ushort4(f2bf(b.x), f2bf(b.y), f2bf(b.z), f2bf(b.w));
}

// Fused: boundary (fp64 dot, parallel over 128 lanes) + mean-pool + bf16 convert.
// One block = 32 t-rows = 4 segments; reads x exactly once.
__launch_bounds__(256)
__global__ void k_prep(const float4* __restrict__ x4, const float4* __restrict__ wb4,
                       const float* __restrict__ bb, float4* __restrict__ pooled4,
                       unsigned short* __restrict__ pooledh, float* __restrict__ bnd,
                       int* __restrict__ cnt){
  __shared__ double ld[4][8][8];          // [seg_l][row_l][16-lane group]
  const int tid  = threadIdx.x;
  const int row0 = blockIdx.x << 5;       // first global t-row of this block
  const double bbv = (double)bb[0];
  #pragma unroll
  for(int it = 0; it < 2; it++){
    const int slot  = (it << 8) + tid;    // 0..511 = (seg_l:4) x (c4:128)
    const int seg_l = slot >> 7;
    const int c4    = slot & 127;
    const float4 w  = wb4[c4];
    const float4* src = x4 + ((size_t)(row0 + (seg_l << 3)) * 128 + c4);
    float4 acc = src[0];
    double p[8];
    p[0] = (double)acc.x*w.x + (double)acc.y*w.y + (double)acc.z*w.z + (double)acc.w*w.w;
    #pragma unroll
    for(int t = 1; t < 8; t++){
      const float4 v = src[(size_t)t * 128];
      acc.x += v.x; acc.y += v.y; acc.z += v.z; acc.w += v.w;
      p[t] = (double)v.x*w.x + (double)v.y*w.y + (double)v.z*w.z + (double)v.w*w.w;
    }
    acc.x *= 0.125f; acc.y *= 0.125f; acc.z *= 0.125f; acc.w *= 0.125f;
    const int u = ((blockIdx.x << 2) + seg_l) * 128 + c4;
    pooled4[u] = acc;
    *(ushort4*)(pooledh + ((size_t)u << 2)) =
        make_ushort4(f2bf(acc.x), f2bf(acc.y), f2bf(acc.z), f2bf(acc.w));
    #pragma unroll
    for(int t = 0; t < 8; t++){
      #pragma unroll
      for(int off = 1; off < 16; off <<= 1) p[t] += __shfl_xor(p[t], off);
    }
    if((c4 & 15) == 0){
      #pragma unroll
      for(int t = 0; t < 8; t++) ld[seg_l][t][c4 >> 4] = p[t];
    }
  }
  __syncthreads();
  if(tid < 32){
    const double* q = ld[tid >> 3][tid & 7];
    double s = bbv;
    #pragma unroll
    for(int h = 0; h < 8; h++) s += q[h];
    const bool f = s > 0.0;
    bnd[row0 + tid] = f ? 1.0f : 0.0f;
    const unsigned long long m = __ballot(f);
    if(tid == 0) atomicAdd(cnt, (int)__popcll(m));
  }
}

// bf16 MFMA distance GEMM, 256x256 tile, 8 waves, BK=32, 4-deep LDS ring.
// DERIVED-WAITS pipeline (T3+T4 proper): fragment ds_reads issued ONE PHASE
// AHEAD; pre-MFMA wait is a COUNTED lgkmcnt (never 0 in steady state), so the
// next phase's LDS reads drain UNDER the current MFMA cluster. 2 barriers/step.
//   A(t): issue afb reads (buf t) + SA(t+3); lgkmcnt(4) -> MFMA upper;
//         vmcnt(6) [buf t+1 staged]; barrier
//   B(t): issue next-set reads (buf t+1) + SB(t+3); lgkmcnt(8) -> MFMA lower; barrier
// XOR-swizzled LDS (linear gload dest + pre-swizzled source + swizzled read).
// XCD slab swizzle for L2 locality. launch_bounds(512,2) for ~256-VGPR budget.
__launch_bounds__(512, 2)
__global__ void k_distx(const unsigned short* __restrict__ Ah,
                        const unsigned short* __restrict__ Bh,
                        const float* __restrict__ enorm,
                        unsigned long long* __restrict__ cand64){
  // 4 ring buffers, each: A 256x32 bf16 (16KB) + B 256x32 (16KB) = 32KB
  __shared__ __align__(16) unsigned short smem[65536];   // 128 KB

  const int tid  = threadIdx.x;
  const int w    = tid >> 6, lane = tid & 63;
  const int wm   = w >> 2,  wn   = w & 3;        // 2x4 wave grid; wave = 128x64 out
  const int c    = lane & 15, q  = lane >> 4;

  const int bid   = blockIdx.x;
  const int xcd   = bid & 7;
  const int local = bid >> 3;                    // 0..255 within XCD
  const int row_t = (xcd << 3) + (local & 7);    // 0..63  (8-row-tile slab per XCD)
  const int col_t = local >> 3;                  // 0..31  (col-major sweep)
  const int rowbase = row_t << 8;
  const int colbase = col_t << 8;

  f32x4 acc[8][4];
  #pragma unroll
  for(int i = 0; i < 8; i++)
    #pragma unroll
    for(int j = 0; j < 4; j++) acc[i][j] = (f32x4){0.f, 0.f, 0.f, 0.f};

  // ---- staging geometry: LDS row = tid>>2 (+128), LDS chunk = tid&3 (16B units).
  // LDS(row, chunk) holds global(row, chunk ^ ((row>>1)&3)) -> pre-swizzle source.
  const int sr  = tid >> 2;                      // 0..127
  const int cg  = (((tid & 3) ^ ((tid >> 3) & 3)) << 3);   // swizzled k-chunk (elements)
  const int wbase = w << 9;                      // wave-uniform LDS base (ushorts)

  const unsigned short* As0 = Ah + (size_t)(rowbase + sr)       * 512 + cg;
  const unsigned short* As1 = Ah + (size_t)(rowbase + 128 + sr) * 512 + cg;
  const unsigned short* Bs0 = Bh + (size_t)(colbase + sr)       * 512 + cg;
  const unsigned short* Bs1 = Bh + (size_t)(colbase + 128 + sr) * 512 + cg;

  // read-side swizzle (byte addrs): chunk_l = q ^ ((row>>1)&3); row&15 == c
  const int chb = ((q ^ ((c >> 1) & 3)) << 4);             // byte offset within row
  const int abA = (wm*128 + c)*64 + chb;                   // A frag byte base
  const int abB = 16384 + (wn*64 + c)*64 + chb;            // B frag byte base

  // fragment sets: ping-pong for {bg, af-upper}; single set for af-lower (afb):
  // afb loaded in A(t), consumed in B(t), reloaded in A(t+1) -> no overlap.
  bf16x8 bgr[2][4], afr[2][4], afb[4];

  #define SA(tt) do{ const int sb_ = ((tt) & 3) << 14; const size_t ko_ = (size_t)(tt) << 5; \
    gload16(As0 + ko_, &smem[sb_ + wbase]);                                                  \
    gload16(As1 + ko_, &smem[sb_ + 4096  + wbase]); }while(0)
  #define SB(tt) do{ const int sb_ = ((tt) & 3) << 14; const size_t ko_ = (size_t)(tt) << 5; \
    gload16(Bs0 + ko_, &smem[sb_ + 8192  + wbase]);                                          \
    gload16(Bs1 + ko_, &smem[sb_ + 12288 + wbase]); }while(0)

  #define DSR8(st, BUF) do{                                       \
    const int vB_ = abB + (BUF);                                  \
    const int vA_ = abA + (BUF);                                  \
    DSR(bgr[st][0], vB_, "0");    DSR(bgr[st][1], vB_, "1024");   \
    DSR(bgr[st][2], vB_, "2048"); DSR(bgr[st][3], vB_, "3072");   \
    DSR(afr[st][0], vA_, "0");    DSR(afr[st][1], vA_, "1024");   \
    DSR(afr[st][2], vA_, "2048"); DSR(afr[st][3], vA_, "3072");   \
  }while(0)

  #define DSR4(BUF) do{                                           \
    const int vA_ = abA + (BUF);                                  \
    DSR(afb[0], vA_, "4096"); DSR(afb[1], vA_, "5120");           \
    DSR(afb[2], vA_, "6144"); DSR(afb[3], vA_, "7168");           \
  }while(0)

  #define MFMA16_A(st) do{ _Pragma("unroll")                                  \
    for(int i = 0; i < 4; i++) _Pragma("unroll")                              \
      for(int j = 0; j < 4; j++)                                              \
        acc[i][j] = __builtin_amdgcn_mfma_f32_16x16x32_bf16(                  \
            afr[st][i], bgr[st][j], acc[i][j], 0, 0, 0); }while(0)
  #define MFMA16_B(st) do{ _Pragma("unroll")                                  \
    for(int i = 0; i < 4; i++) _Pragma("unroll")                              \
      for(int j = 0; j < 4; j++)                                              \
        acc[i+4][j] = __builtin_amdgcn_mfma_f32_16x16x32_bf16(                \
            afb[i], bgr[st][j], acc[i+4][j], 0, 0, 0); }while(0)

  // Phase A of step t (set st): afb read-ahead + optional SA(t+3); counted lgkm;
  // MFMA upper half; staging guarantee for buf t+1; barrier.
  #define PH_A(t_, st, DOST, VMN) do{               \
    DSR4(((t_) & 3) << 15);                         \
    if(DOST) SA((t_) + 3);                          \
    WAITLGK(4); SCHED0();                           \
    SETP1(); MFMA16_A(st); SETP0();                 \
    WAITVM(VMN);                                    \
    SBAR();                                         \
  }while(0)

  // Phase B of step t (set st): next-set read-ahead from buf t+1 + optional SB(t+3);
  // counted lgkm; MFMA lower half; barrier.
  #define PH_B(t_, st, DOST) do{                    \
    DSR8(1 - (st), (((t_) + 1) & 3) << 15);         \
    if(DOST) SB((t_) + 3);                          \
    WAITLGK(8); SCHED0();                           \
    SETP1(); MFMA16_B(st); SETP0();                 \
    SBAR();                                         \
  }while(0)

  #define PH_B_LAST(st) do{                         \
    WAITLGK(0); SCHED0();                           \
    SETP1(); MFMA16_B(st); SETP0();                 \
  }while(0)

  // prologue: stage steps 0,1,2 (12 loads); buf0 landed (vmcnt 8); barrier;
  // then pre-load set0 fragments from buf0 (8 lgkm outstanding entering A(0)).
  SA(0); SB(0); SA(1); SB(1); SA(2); SB(2);
  WAITVM(8);
  SBAR();
  DSR8(0, 0);

  // steady: t=0..12 stage t+3; vmcnt(6) keeps bufs t+2,t+3 (+SA t+3) in flight
  #pragma unroll 1
  for(int u = 0; u < 6; ++u){
    const int t = u << 1;
    PH_A(t,     0, 1, 6);  PH_B(t,     0, 1);
    PH_A(t + 1, 1, 1, 6);  PH_B(t + 1, 1, 1);
  }
  PH_A(12, 0, 1, 6);  PH_B(12, 0, 1);     // stages buf 15
  PH_A(13, 1, 0, 4);  PH_B(13, 1, 0);     // buf14 guaranteed
  PH_A(14, 0, 0, 0);  PH_B(14, 0, 0);     // buf15 guaranteed
  PH_A(15, 1, 0, 0);  PH_B_LAST(1);

  #undef SA
  #undef SB
  #undef DSR8
  #undef DSR4
  #undef MFMA16_A
  #undef MFMA16_B
  #undef PH_A
  #undef PH_B
  #undef PH_B_LAST

  // epilogue: dist = enorm - 2*dot; in-thread top-2 over 4 j-cols, 4-step
  // butterfly over 16 c-lanes -> top-2 per 64-col group; lane c==0 stores u64.
  float en[4];
  #pragma unroll
  for(int j = 0; j < 4; j++) en[j] = enorm[colbase + wn*64 + j*16 + c];

  #pragma unroll
  for(int i = 0; i < 8; i++){
    #pragma unroll
    for(int r = 0; r < 4; r++){
      unsigned int k1 = 0xffffffffu, k2 = 0xffffffffu;
      #pragma unroll
      for(int j = 0; j < 4; j++){
        const float d = fmaf(-2.0f, acc[i][j][r], en[j]);
        const unsigned int col = (unsigned int)(colbase + wn*64 + j*16 + c);
        const unsigned int key = (fsort(d) & 0xffffe000u) | col;
        if(key < k1){ k2 = k1; k1 = key; } else if(key < k2){ k2 = key; }
      }
      #pragma unroll
      for(int off = 1; off < 16; off <<= 1){
        const unsigned int o1 = __shfl_xor(k1, off);
        const unsigned int o2 = __shfl_xor(k2, off);
        if(o1 < k1){ k2 = min(k1, o2); k1 = o1; }
        else       { k2 = min(k2, o1); }
      }
      if(c == 0){
        const int row = rowbase + wm*128 + i*16 + (q << 2) + r;
        cand64[((size_t)row << 7) + (col_t << 2) + wn] =
            ((unsigned long long)k2 << 32) | k1;
      }
    }
  }
}

// fp64 rescore of candidates within margin of min -> exact argmin + per-row loss term
__launch_bounds__(256)
__global__ void k_fixup(const float* __restrict__ pooled, const float* __restrict__ emb,
                        const unsigned long long* __restrict__ cand64,
                        int* __restrict__ idxf, double* __restrict__ part){
  const int lane = threadIdx.x & 63, wv = threadIdx.x >> 6;
  const int row = (blockIdx.x << 2) + wv;
  const ulonglong2* cr = (const ulonglong2*)(cand64 + ((size_t)row << 7));
  const ulonglong2 v = cr[lane];
  unsigned int ks[4];
  ks[0] = (unsigned int)v.x; ks[1] = (unsigned int)(v.x >> 32);
  ks[2] = (unsigned int)v.y; ks[3] = (unsigned int)(v.y >> 32);
  unsigned int mn = min(min(ks[0], ks[1]), min(ks[2], ks[3]));
  #pragma unroll
  for(int off = 32; off; off >>= 1) mn = min(mn, (unsigned int)__shfl_xor(mn, off));
  const float thr = funsort(mn & 0xffffe000u) + 0.01f;   // covers bf16 + key-trunc error

  double bestd = 1e300; int besti = 0x7fffffff;
  const float4* p4 = (const float4*)(pooled + ((size_t)row << 9));
  const float4 pa = p4[lane << 1], pb = p4[(lane << 1) + 1];
  #pragma unroll
  for(int g = 0; g < 4; g++){
    const bool flag = funsort(ks[g] & 0xffffe000u) <= thr;
    unsigned long long mask = __ballot(flag);
    while(mask){
      const int l = __ffsll(mask) - 1;
      mask &= mask - 1;
      const int code = (int)(__shfl(ks[g], l) & 0x1fffu);
      const float4* e4 = (const float4*)(emb + ((size_t)code << 9));
      const float4 ea = e4[lane << 1], eb = e4[(lane << 1) + 1];
      double s = 0.0, d;
      d = (double)pa.x - ea.x; s += d * d;  d = (double)pa.y - ea.y; s += d * d;
      d = (double)pa.z - ea.z; s += d * d;  d = (double)pa.w - ea.w; s += d * d;
      d = (double)pb.x - eb.x; s += d * d;  d = (double)pb.y - eb.y; s += d * d;
      d = (double)pb.z - eb.z; s += d * d;  d = (double)pb.w - eb.w; s += d * d;
      #pragma unroll
      for(int off = 32; off; off >>= 1) s += __shfl_xor(s, off);
      if(s < bestd || (s == bestd && code < besti)){ bestd = s; besti = code; }
    }
  }
  __shared__ double se[4];
  if(lane == 0){ idxf[row] = besti; se[wv] = bestd; }
  __syncthreads();
  if(threadIdx.x == 0) part[blockIdx.x] = se[0] + se[1] + se[2] + se[3];
}

__global__ void k_loss(const double* __restrict__ part, const int* __restrict__ cnt,
                       float* __restrict__ out_loss){
  const int tid = threadIdx.x;
  double s = 0.0;
  for(int i = tid; i < 4096; i += 256) s += part[i];
  #pragma unroll
  for(int off = 32; off; off >>= 1) s += __shfl_xor(s, off);
  __shared__ double sb[4];
  if((tid & 63) == 0) sb[tid >> 6] = s;
  __syncthreads();
  if(tid == 0){
    const double e  = sb[0] + sb[1] + sb[2] + sb[3];
    const double el = e / (double)((size_t)N_ * 512);
    const double bm = (double)(*cnt) / 131072.0 - 0.125;
    const double loss = 0.25 * el + 0.01 * bm * bm;
    *out_loss = (float)loss;
  }
}

// expand codes over SPAN: one wave per segment, 16 coalesced 1KB stores
__launch_bounds__(256)
__global__ void k_expand(const float4* __restrict__ emb4, const int* __restrict__ idxf,
                         float4* __restrict__ q4, float* __restrict__ idxo){
  const int lane = threadIdx.x & 63, wv = threadIdx.x >> 6;
  const int seg = (blockIdx.x << 2) + wv;      // 0..16383
  const int idx = idxf[seg];
  const float4 a = emb4[idx * 128 + (lane << 1)];
  const float4 b = emb4[idx * 128 + (lane << 1) + 1];
  float4* dst = q4 + ((size_t)seg << 10);
  #pragma unroll
  for(int t = 0; t < 8; t++){
    dst[t * 128 + (lane << 1)]     = a;
    dst[t * 128 + (lane << 1) + 1] = b;
  }
  if(lane < 8) idxo[(seg << 3) + lane] = (float)idx;
}

extern "C" void kernel_launch(void* const* d_in, const int* in_sizes, int n_in,
                              void* d_out, int out_size, void* d_ws, size_t ws_size,
                              hipStream_t stream){
  const float* x   = (const float*)d_in[0];
  const float* emb = (const float*)d_in[1];
  const float* wb  = (const float*)d_in[2];
  const float* bb  = (const float*)d_in[3];
  float* out = (float*)d_out;

  // small workspace fields
  char* ws = (char*)d_ws;
  int*    cnt   = (int*)(ws + 0);
  double* part  = (double*)(ws + 64);       // 4096 doubles
  float*  enorm = (float*)(ws + 32832);     // 8192 floats
  int*    idxf  = (int*)(ws + 65600);       // 16384 ints

  // big scratch inside the quantized_out region (overwritten last by k_expand)
  float*              pooled  = (float*)d_out;                                        // 32 MB @ 0
  unsigned long long* cand64  = (unsigned long long*)((char*)d_out + (48ull  << 20)); // 16 MB @ 48M
  unsigned short*     pooledh = (unsigned short*)((char*)d_out + (80ull  << 20));     // 16 MB @ 80M
  unsigned short*     embh    = (unsigned short*)((char*)d_out + (100ull << 20));     //  8 MB @ 100M

  float* bnd   = out + BND_OFF;
  float* idxo  = out + IDX_OFF;
  float* lossp = out + LOSS_OFF;

  hipLaunchKernelGGL(k_embnorm, dim3(2048),  dim3(256), 0, stream, (const float4*)emb, enorm, embh, cnt);
  hipLaunchKernelGGL(k_prep,    dim3(4096),  dim3(256), 0, stream, (const float4*)x, (const float4*)wb,
                     bb, (float4*)pooled, pooledh, bnd, cnt);
  hipLaunchKernelGGL(k_distx,   dim3(2048),  dim3(512), 0, stream, pooledh, embh, enorm, cand64);
  hipLaunchKernelGGL(k_fixup,   dim3(4096),  dim3(256), 0, stream, pooled, emb, cand64, idxf, part);
  hipLaunchKernelGGL(k_loss,    dim3(1),     dim3(256), 0, stream, part, cnt, lossp);
  hipLaunchKernelGGL(k_expand,  dim3(4096),  dim3(256), 0, stream, (const float4*)emb, idxf, (float4*)d_out, idxo);
}